// Round 1
// baseline (348.312 us; speedup 1.0000x reference)
//
#include <hip/hip_runtime.h>

#define B_  64
#define T_  1000
#define DV_ 512
#define DQ_ 1024
#define U_  128
#define F_  32
#define KS_ 31
#define P_  16     // context partial chunks per batch
#define CT_ 63     // t per chunk (last chunk 55)

typedef __attribute__((ext_vector_type(8))) short short8;
typedef __attribute__((ext_vector_type(4))) float f32x4;

// round-to-nearest-even f32 -> bf16 (bit trick), packed pair
__device__ __forceinline__ unsigned pk2(float a, float b) {
    union { float f; unsigned u; } x, y;
    x.f = a; y.f = b;
    unsigned ra = (x.u + 0x7FFFu + ((x.u >> 16) & 1u)) >> 16;
    unsigned rb = (y.u + 0x7FFFu + ((y.u >> 16) & 1u)) >> 16;
    return (ra & 0xFFFFu) | (rb << 16);
}

__device__ __forceinline__ float fast_tanh(float x) {
    return 1.0f - 2.0f / (__expf(2.0f * x) + 1.0f);
}

// pack two float4 (8 consecutive k) into bf16 short8
__device__ __forceinline__ short8 pk8(float4 f0, float4 f1) {
    int4 q;
    q.x = pk2(f0.x, f0.y); q.y = pk2(f0.z, f0.w);
    q.z = pk2(f1.x, f1.y); q.w = pk2(f1.z, f1.w);
    return *(short8*)&q;
}

// ---------------------------------------------------------------------------
// Merged prep: blocks 0..8 repack Wm/Wl to bf16 B-frag layout.
// Blocks 9..72: qb k-split partials. Block id -> (slab s of 64 k, batch-group
// bg of 16 b). Wq traffic = 4x512KB total (vs 64x before); 64 blocks stream
// in parallel. partQ[s][b][u] reduced inside score_kernel (with bq+bm).
// ---------------------------------------------------------------------------
__global__ __launch_bounds__(1024) void prep_kernel(
    const float* __restrict__ Wm, const float* __restrict__ Wl,
    const float* __restrict__ query, const float* __restrict__ Wq,
    short* __restrict__ WmX, short* __restrict__ WlX, float* __restrict__ partQ)
{
    __shared__ float sh[1024];
    int blk = blockIdx.x, tid = threadIdx.x;
    if (blk < 9) {
        int g = blk * 1024 + tid;
        if (g < 8192) {
            int kc = g >> 9, e = g & 511;
            int n = e >> 2, q = e & 3;
            int kb = kc * 32 + q * 8;
            int4 p;
            p.x = pk2(Wm[(kb + 0) * U_ + n], Wm[(kb + 1) * U_ + n]);
            p.y = pk2(Wm[(kb + 2) * U_ + n], Wm[(kb + 3) * U_ + n]);
            p.z = pk2(Wm[(kb + 4) * U_ + n], Wm[(kb + 5) * U_ + n]);
            p.w = pk2(Wm[(kb + 6) * U_ + n], Wm[(kb + 7) * U_ + n]);
            ((int4*)WmX)[g] = p;
        } else if (g < 8704) {
            int e = g - 8192;
            int n = e >> 2, q = e & 3;
            int kb = q * 8;
            int4 p;
            p.x = pk2(Wl[(kb + 0) * U_ + n], Wl[(kb + 1) * U_ + n]);
            p.y = pk2(Wl[(kb + 2) * U_ + n], Wl[(kb + 3) * U_ + n]);
            p.z = pk2(Wl[(kb + 4) * U_ + n], Wl[(kb + 5) * U_ + n]);
            p.w = pk2(Wl[(kb + 6) * U_ + n], Wl[(kb + 7) * U_ + n]);
            ((int4*)WlX)[e] = p;
        }
    } else {
        int id = blk - 9;          // 0..63
        int s  = id >> 2;          // k-slab 0..15  (64 k each)
        int bg = id & 3;           // batch group 0..3 (16 b each)
        // stage query tile [16 b][64 k]
        sh[tid] = query[(size_t)(bg * 16 + (tid >> 6)) * DQ_ + s * 64 + (tid & 63)];
        __syncthreads();
        int u = tid & 127, h = tid >> 7;   // h 0..7, each handles 2 batches
        const float* wp = Wq + (size_t)(s * 64) * U_ + u;
        const float* q0 = sh + (h * 2) * 64;
        const float* q1 = q0 + 64;
        float a0 = 0.f, a1 = 0.f;
#pragma unroll 8
        for (int k = 0; k < 64; ++k) {
            float w = wp[(size_t)k * U_];
            a0 += q0[k] * w; a1 += q1[k] * w;
        }
        int b0i = bg * 16 + h * 2;
        partQ[s * 8192 + b0i * 128 + u]       = a0;
        partQ[s * 8192 + (b0i + 1) * 128 + u] = a1;
    }
}

// ---------------------------------------------------------------------------
// scores[r], r=b*T+t: tanh(values@Wm + qb + tanh(conv(prev)@Wl)) @ Wv + bv
// 64 rows/block (1000 blocks), 4 waves; each wave owns ONE 16-row group x
// 128 cols. Register diet for occupancy: acc 32 VGPR, A dist-2 queue 24,
// B single in-place-reloaded queue 32 -> target <=128 VGPR, 4 waves/SIMD,
// all 1000 blocks resident in one round. Barrier-free streaming K-loop.
// ---------------------------------------------------------------------------
__global__ __launch_bounds__(256, 4) void score_kernel(
    const float* __restrict__ values, const float* __restrict__ prev,
    const float* __restrict__ Wc, const float* __restrict__ Wv,
    const float* __restrict__ bv, const short* __restrict__ WmX,
    const short* __restrict__ WlX, const float* __restrict__ partQ,
    const float* __restrict__ bq, const float* __restrict__ bm,
    float* __restrict__ scores)
{
    __shared__ float WcS[KS_ * F_];
    __shared__ short AsL[64 * 32];     // conv result, A-frag layout + XOR swizzle
    __shared__ float qbS[2 * U_];
    __shared__ float WvS[U_];

    const int tid = threadIdx.x;
    const int r0 = blockIdx.x * 64;
    const int b0 = r0 / T_;
    const int b1 = (r0 + 63) / T_;

    for (int i = tid; i < KS_ * F_; i += 256) WcS[i] = Wc[i];
    if (tid < U_) WvS[tid] = Wv[tid];
    {
        int u = tid & (U_ - 1);
        int bb = (tid < U_) ? b0 : b1;
        float s = bq[u] + bm[u];
#pragma unroll
        for (int sl = 0; sl < 16; ++sl) s += partQ[sl * 8192 + bb * 128 + u];
        qbS[tid] = s;
    }

    const int wv = tid >> 6, lane = tid & 63;
    const int quad = lane >> 4, m15 = lane & 15;
    const int row0 = wv * 16 + m15;          // this wave's A row in tile
    const float* aP = values + (size_t)(r0 + row0) * DV_ + quad * 8;
    const int4* bW  = (const int4*)WmX + m15 * 4 + quad;
    const int4* blW = (const int4*)WlX + m15 * 4 + quad;

    // prefetch: A for kc=0,1 ; B for kc=0 (stay in flight across conv/barriers)
    float4 aq0[2], aq1[2], aq2[2];
    int4 bf[8];
    aq0[0] = *(const float4*)(aP);      aq0[1] = *(const float4*)(aP + 4);
    aq1[0] = *(const float4*)(aP + 32); aq1[1] = *(const float4*)(aP + 36);
#pragma unroll
    for (int c = 0; c < 8; ++c) bf[c] = bW[c * 64];

    __syncthreads();   // WcS / qbS / WvS ready

    // location conv: loc_pre[i,f] = sum_k prev[b, t+k-15]*Wc[k,f] (SAME pad)
    // 256 (row, 8-filter-group) items, 1 per thread.
    {
        int i = tid & 63, fg = tid >> 6;
        int r = r0 + i;
        int b = r / T_;
        int t = r - b * T_;
        const float* pv = prev + b * T_;
        float a8[8] = {};
#pragma unroll
        for (int k = 0; k < KS_; ++k) {
            int tt = t + k - 15;
            float p = ((unsigned)tt < (unsigned)T_) ? pv[tt] : 0.f;
#pragma unroll
            for (int j = 0; j < 8; ++j) a8[j] += p * WcS[k * F_ + fg * 8 + j];
        }
        int4 pq;
        pq.x = pk2(a8[0], a8[1]); pq.y = pk2(a8[2], a8[3]);
        pq.z = pk2(a8[4], a8[5]); pq.w = pk2(a8[6], a8[7]);
        ((int4*)AsL)[i * 4 + (fg ^ ((i >> 1) & 3))] = pq;   // XOR swizzle
    }
    __syncthreads();

    // loc GEMM (K=32) into acc, then acc = qb + tanh(acc)
    f32x4 acc[8] = {};
    {
        short8 afl = ((const short8*)AsL)[row0 * 4 + (quad ^ ((row0 >> 1) & 3))];
#pragma unroll
        for (int c = 0; c < 8; ++c) {
            int4 bl = blW[c * 64];
            acc[c] = __builtin_amdgcn_mfma_f32_16x16x32_bf16(afl, *(short8*)&bl, acc[c], 0, 0, 0);
        }
        int qoff[4];
#pragma unroll
        for (int v = 0; v < 4; ++v) {
            int r = r0 + wv * 16 + quad * 4 + v;
            qoff[v] = ((r / T_) == b0) ? 0 : U_;
        }
#pragma unroll
        for (int c = 0; c < 8; ++c) {
            int col = c * 16 + m15;
#pragma unroll
            for (int v = 0; v < 4; ++v)
                acc[c][v] = qbS[qoff[v] + col] + fast_tanh(acc[c][v]);
        }
    }

    // barrier-free streaming main loop: A dist-2 queue, B dist-1 via
    // in-place reload (bf[c] reused right after its MFMA consumes it).
#pragma unroll
    for (int kc = 0; kc < 16; ++kc) {
        if (kc + 2 < 16) {
            aq2[0] = *(const float4*)(aP + (kc + 2) * 32);
            aq2[1] = *(const float4*)(aP + (kc + 2) * 32 + 4);
        }
        short8 af = pk8(aq0[0], aq0[1]);
#pragma unroll
        for (int c = 0; c < 8; ++c) {
            acc[c] = __builtin_amdgcn_mfma_f32_16x16x32_bf16(af, *(short8*)&bf[c], acc[c], 0, 0, 0);
            if (kc + 1 < 16) bf[c] = bW[(kc + 1) * 512 + c * 64];
        }
        aq0[0] = aq1[0]; aq0[1] = aq1[1];
        aq1[0] = aq2[0]; aq1[1] = aq2[1];
    }

    // epilogue: score = sum_col tanh(acc)*Wv[col] + bv
    float psum[4] = {};
#pragma unroll
    for (int c = 0; c < 8; ++c) {
        int col = c * 16 + m15;
        float wvv = WvS[col];
#pragma unroll
        for (int v = 0; v < 4; ++v)
            psum[v] += fast_tanh(acc[c][v]) * wvv;
    }
#pragma unroll
    for (int off = 1; off < 16; off <<= 1) {
#pragma unroll
        for (int v = 0; v < 4; ++v) psum[v] += __shfl_xor(psum[v], off);
    }
    if (m15 == 0) {
        float bvv = bv[0];
#pragma unroll
        for (int v = 0; v < 4; ++v)
            scores[r0 + wv * 16 + quad * 4 + v] = psum[v] + bvv;
    }
}

// ---------------------------------------------------------------------------
// Fused softmax + context phase 1. Each (b,p) block re-derives the row
// max/sum from scores (4 KB, L2-hot, deterministic & identical across p),
// writes attention weights for its chunk, and accumulates the weighted
// partial context. Removes the separate softmax launch.
// ---------------------------------------------------------------------------
__global__ __launch_bounds__(256) void ctx1_kernel(
    const float* __restrict__ values, const float* __restrict__ scores,
    float* __restrict__ attw, float* __restrict__ part)
{
    __shared__ float wS[CT_];
    __shared__ float4 ps[128];
    __shared__ float red[4];
    int b = blockIdx.x, p = blockIdx.y, tid = threadIdx.x;
    const float* sb = scores + b * T_;

    // full-row softmax normalization (max + sum)
    float v[4];
    int tv[4];
#pragma unroll
    for (int i = 0; i < 4; ++i) {
        int t = tid + i * 256;
        tv[i] = t;
        v[i] = (t < T_) ? sb[t] : -1e30f;
    }
    float mx = fmaxf(fmaxf(v[0], v[1]), fmaxf(v[2], v[3]));
#pragma unroll
    for (int off = 32; off >= 1; off >>= 1) mx = fmaxf(mx, __shfl_xor(mx, off));
    int wvi = tid >> 6, lane = tid & 63;
    if (lane == 0) red[wvi] = mx;
    __syncthreads();
    mx = fmaxf(fmaxf(red[0], red[1]), fmaxf(red[2], red[3]));
    float sum = 0.f;
#pragma unroll
    for (int i = 0; i < 4; ++i)
        sum += (tv[i] < T_) ? __expf(v[i] - mx) : 0.f;
#pragma unroll
    for (int off = 32; off >= 1; off >>= 1) sum += __shfl_xor(sum, off);
    __syncthreads();
    if (lane == 0) red[wvi] = sum;
    __syncthreads();
    float inv = 1.0f / (red[0] + red[1] + red[2] + red[3]);

    // this block's chunk: weights -> LDS + attw output
    int t0 = p * CT_;
    int len = (T_ - t0 < CT_) ? (T_ - t0) : CT_;
    if (tid < len) {
        float e = __expf(sb[t0 + tid] - mx) * inv;
        wS[tid] = e;
        attw[b * T_ + t0 + tid] = e;
    }
    __syncthreads();

    int cl = tid & 127, tp = tid >> 7;
    const float* vp = values + ((size_t)b * T_ + t0) * DV_ + cl * 4;
    float4 a = {0.f, 0.f, 0.f, 0.f};
#pragma unroll 4
    for (int t = tp; t < len; t += 2) {
        float4 vv = *(const float4*)(vp + (size_t)t * DV_);
        float wt = wS[t];
        a.x += wt * vv.x; a.y += wt * vv.y; a.z += wt * vv.z; a.w += wt * vv.w;
    }
    if (tp == 1) ps[cl] = a;
    __syncthreads();
    if (tp == 0) {
        float4 o = ps[cl];
        o.x += a.x; o.y += a.y; o.z += a.z; o.w += a.w;
        *(float4*)(part + ((size_t)(b * P_ + p)) * DV_ + cl * 4) = o;
    }
}

// context phase 2: ctx[b,d] = sum_p partial[b,p,d]
__global__ void ctx2_kernel(const float* __restrict__ part, float* __restrict__ ctx) {
    int b = blockIdx.x, tid = threadIdx.x;   // 128 threads, float4 each
    const float* pp = part + (size_t)b * P_ * DV_ + tid * 4;
    float4 s = {0.f, 0.f, 0.f, 0.f};
#pragma unroll
    for (int p = 0; p < P_; ++p) {
        float4 v = *(const float4*)(pp + (size_t)p * DV_);
        s.x += v.x; s.y += v.y; s.z += v.z; s.w += v.w;
    }
    *(float4*)(ctx + (size_t)b * DV_ + tid * 4) = s;
}

extern "C" void kernel_launch(void* const* d_in, const int* in_sizes, int n_in,
                              void* d_out, int out_size, void* d_ws, size_t ws_size,
                              hipStream_t stream) {
    const float* query  = (const float*)d_in[0];
    const float* values = (const float*)d_in[1];
    const float* prev   = (const float*)d_in[2];
    const float* Wq     = (const float*)d_in[3];
    const float* bq     = (const float*)d_in[4];
    const float* Wm     = (const float*)d_in[5];
    const float* bm     = (const float*)d_in[6];
    const float* Wv     = (const float*)d_in[7];
    const float* bv     = (const float*)d_in[8];
    const float* Wc     = (const float*)d_in[9];
    const float* Wl     = (const float*)d_in[10];

    float* out  = (float*)d_out;
    float* ctx  = out;                 // [64,512]
    float* attw = out + B_ * DV_;      // [64,1000,1]

    char* ws = (char*)d_ws;
    // ctx partials [0, 2M) -- ALIASED with qb partials [0, 512K):
    // partQ is dead once score_kernel completes; ctx1 writes part afterwards.
    float* part   = (float*)(ws);                              // 2 MB
    float* partQ  = (float*)(ws);                              // 512 KB (alias)
    float* scores = (float*)(ws + 2097152);                    // 256 KB
    short* WmX    = (short*)(ws + 2097152 + 262144);           // 128 KB
    short* WlX    = (short*)(ws + 2097152 + 262144 + 131072);  // 8 KB

    prep_kernel<<<73, 1024, 0, stream>>>(Wm, Wl, query, Wq, WmX, WlX, partQ);
    score_kernel<<<1000, 256, 0, stream>>>(values, prev, Wc, Wv, bv, WmX, WlX,
                                           partQ, bq, bm, scores);
    ctx1_kernel<<<dim3(B_, P_), 256, 0, stream>>>(values, scores, attw, part);
    ctx2_kernel<<<B_, 128, 0, stream>>>(part, ctx);
}

// Round 3
// 335.594 us; speedup vs baseline: 1.0379x; 1.0379x over previous
//
#include <hip/hip_runtime.h>

#define B_  64
#define T_  1000
#define DV_ 512
#define DQ_ 1024
#define U_  128
#define F_  32
#define KS_ 31
#define P_  16     // context partial chunks per batch
#define CT_ 63     // t per chunk (last chunk 55)

typedef __attribute__((ext_vector_type(8))) short short8;
typedef __attribute__((ext_vector_type(4))) float f32x4;

// round-to-nearest-even f32 -> bf16 (bit trick), packed pair
__device__ __forceinline__ unsigned pk2(float a, float b) {
    union { float f; unsigned u; } x, y;
    x.f = a; y.f = b;
    unsigned ra = (x.u + 0x7FFFu + ((x.u >> 16) & 1u)) >> 16;
    unsigned rb = (y.u + 0x7FFFu + ((y.u >> 16) & 1u)) >> 16;
    return (ra & 0xFFFFu) | (rb << 16);
}

__device__ __forceinline__ float fast_tanh(float x) {
    return 1.0f - 2.0f / (__expf(2.0f * x) + 1.0f);
}

// pack two float4 (8 consecutive k) into bf16 short8
__device__ __forceinline__ short8 pk8(float4 f0, float4 f1) {
    int4 q;
    q.x = pk2(f0.x, f0.y); q.y = pk2(f0.z, f0.w);
    q.z = pk2(f1.x, f1.y); q.w = pk2(f1.z, f1.w);
    return *(short8*)&q;
}

// ---------------------------------------------------------------------------
// Merged prep: blocks 0..8 repack Wm/Wl to bf16 B-frag layout.
// Blocks 9..72: qb k-split partials. Block id -> (slab s of 64 k, batch-group
// bg of 16 b). Wq traffic = 4x512KB total; 64 blocks stream in parallel.
// partQ[s][b][u] reduced inside score_kernel (with bq+bm).
// ---------------------------------------------------------------------------
__global__ __launch_bounds__(1024) void prep_kernel(
    const float* __restrict__ Wm, const float* __restrict__ Wl,
    const float* __restrict__ query, const float* __restrict__ Wq,
    short* __restrict__ WmX, short* __restrict__ WlX, float* __restrict__ partQ)
{
    __shared__ float sh[1024];
    int blk = blockIdx.x, tid = threadIdx.x;
    if (blk < 9) {
        int g = blk * 1024 + tid;
        if (g < 8192) {
            int kc = g >> 9, e = g & 511;
            int n = e >> 2, q = e & 3;
            int kb = kc * 32 + q * 8;
            int4 p;
            p.x = pk2(Wm[(kb + 0) * U_ + n], Wm[(kb + 1) * U_ + n]);
            p.y = pk2(Wm[(kb + 2) * U_ + n], Wm[(kb + 3) * U_ + n]);
            p.z = pk2(Wm[(kb + 4) * U_ + n], Wm[(kb + 5) * U_ + n]);
            p.w = pk2(Wm[(kb + 6) * U_ + n], Wm[(kb + 7) * U_ + n]);
            ((int4*)WmX)[g] = p;
        } else if (g < 8704) {
            int e = g - 8192;
            int n = e >> 2, q = e & 3;
            int kb = q * 8;
            int4 p;
            p.x = pk2(Wl[(kb + 0) * U_ + n], Wl[(kb + 1) * U_ + n]);
            p.y = pk2(Wl[(kb + 2) * U_ + n], Wl[(kb + 3) * U_ + n]);
            p.z = pk2(Wl[(kb + 4) * U_ + n], Wl[(kb + 5) * U_ + n]);
            p.w = pk2(Wl[(kb + 6) * U_ + n], Wl[(kb + 7) * U_ + n]);
            ((int4*)WlX)[e] = p;
        }
    } else {
        int id = blk - 9;          // 0..63
        int s  = id >> 2;          // k-slab 0..15  (64 k each)
        int bg = id & 3;           // batch group 0..3 (16 b each)
        // stage query tile [16 b][64 k]
        sh[tid] = query[(size_t)(bg * 16 + (tid >> 6)) * DQ_ + s * 64 + (tid & 63)];
        __syncthreads();
        int u = tid & 127, h = tid >> 7;   // h 0..7, each handles 2 batches
        const float* wp = Wq + (size_t)(s * 64) * U_ + u;
        const float* q0 = sh + (h * 2) * 64;
        const float* q1 = q0 + 64;
        float a0 = 0.f, a1 = 0.f;
#pragma unroll 8
        for (int k = 0; k < 64; ++k) {
            float w = wp[(size_t)k * U_];
            a0 += q0[k] * w; a1 += q1[k] * w;
        }
        int b0i = bg * 16 + h * 2;
        partQ[s * 8192 + b0i * 128 + u]       = a0;
        partQ[s * 8192 + (b0i + 1) * 128 + u] = a1;
    }
}

// ---------------------------------------------------------------------------
// scores[r], r=b*T+t: tanh(values@Wm + qb + tanh(conv(prev)@Wl)) @ Wv + bv
// 64 rows/block (1000 blocks), 4 waves; each wave owns ONE 16-row group x
// 128 cols. launch_bounds(256,3): ~170-reg budget -> no spills (the (256,4)
// cap forced a 64+64 arch/acc split on the unified file and spilled 250 MB
// to scratch). Barrier-free streaming K-loop: A dist-2, B in-place dist-1.
// ---------------------------------------------------------------------------
__global__ __launch_bounds__(256, 3) void score_kernel(
    const float* __restrict__ values, const float* __restrict__ prev,
    const float* __restrict__ Wc, const float* __restrict__ Wv,
    const float* __restrict__ bv, const short* __restrict__ WmX,
    const short* __restrict__ WlX, const float* __restrict__ partQ,
    const float* __restrict__ bq, const float* __restrict__ bm,
    float* __restrict__ scores)
{
    __shared__ float WcS[KS_ * F_];
    __shared__ short AsL[64 * 32];     // conv result, A-frag layout + XOR swizzle
    __shared__ float qbS[2 * U_];
    __shared__ float WvS[U_];

    const int tid = threadIdx.x;
    const int r0 = blockIdx.x * 64;
    const int b0 = r0 / T_;
    const int b1 = (r0 + 63) / T_;

    for (int i = tid; i < KS_ * F_; i += 256) WcS[i] = Wc[i];
    if (tid < U_) WvS[tid] = Wv[tid];
    {
        int u = tid & (U_ - 1);
        int bb = (tid < U_) ? b0 : b1;
        float s = bq[u] + bm[u];
#pragma unroll
        for (int sl = 0; sl < 16; ++sl) s += partQ[sl * 8192 + bb * 128 + u];
        qbS[tid] = s;
    }

    const int wv = tid >> 6, lane = tid & 63;
    const int quad = lane >> 4, m15 = lane & 15;
    const int row0 = wv * 16 + m15;          // this wave's A row in tile
    const float* aP = values + (size_t)(r0 + row0) * DV_ + quad * 8;
    const int4* bW  = (const int4*)WmX + m15 * 4 + quad;
    const int4* blW = (const int4*)WlX + m15 * 4 + quad;

    // prefetch: A for kc=0,1 ; B for kc=0 (stay in flight across conv/barriers)
    float4 aq0[2], aq1[2], aq2[2];
    int4 bf[8];
    aq0[0] = *(const float4*)(aP);      aq0[1] = *(const float4*)(aP + 4);
    aq1[0] = *(const float4*)(aP + 32); aq1[1] = *(const float4*)(aP + 36);
#pragma unroll
    for (int c = 0; c < 8; ++c) bf[c] = bW[c * 64];

    __syncthreads();   // WcS / qbS / WvS ready

    // location conv: loc_pre[i,f] = sum_k prev[b, t+k-15]*Wc[k,f] (SAME pad)
    // 256 (row, 8-filter-group) items, 1 per thread.
    {
        int i = tid & 63, fg = tid >> 6;
        int r = r0 + i;
        int b = r / T_;
        int t = r - b * T_;
        const float* pv = prev + b * T_;
        float a8[8] = {};
#pragma unroll
        for (int k = 0; k < KS_; ++k) {
            int tt = t + k - 15;
            float p = ((unsigned)tt < (unsigned)T_) ? pv[tt] : 0.f;
#pragma unroll
            for (int j = 0; j < 8; ++j) a8[j] += p * WcS[k * F_ + fg * 8 + j];
        }
        int4 pq;
        pq.x = pk2(a8[0], a8[1]); pq.y = pk2(a8[2], a8[3]);
        pq.z = pk2(a8[4], a8[5]); pq.w = pk2(a8[6], a8[7]);
        ((int4*)AsL)[i * 4 + (fg ^ ((i >> 1) & 3))] = pq;   // XOR swizzle
    }
    __syncthreads();

    // loc GEMM (K=32) into acc, then acc = qb + tanh(acc)
    f32x4 acc[8] = {};
    {
        short8 afl = ((const short8*)AsL)[row0 * 4 + (quad ^ ((row0 >> 1) & 3))];
#pragma unroll
        for (int c = 0; c < 8; ++c) {
            int4 bl = blW[c * 64];
            acc[c] = __builtin_amdgcn_mfma_f32_16x16x32_bf16(afl, *(short8*)&bl, acc[c], 0, 0, 0);
        }
        int qoff[4];
#pragma unroll
        for (int v = 0; v < 4; ++v) {
            int r = r0 + wv * 16 + quad * 4 + v;
            qoff[v] = ((r / T_) == b0) ? 0 : U_;
        }
#pragma unroll
        for (int c = 0; c < 8; ++c) {
            int col = c * 16 + m15;
#pragma unroll
            for (int v = 0; v < 4; ++v)
                acc[c][v] = qbS[qoff[v] + col] + fast_tanh(acc[c][v]);
        }
    }

    // barrier-free streaming main loop: A dist-2 queue, B dist-1 via
    // in-place reload (bf[c] reused right after its MFMA consumes it).
#pragma unroll
    for (int kc = 0; kc < 16; ++kc) {
        if (kc + 2 < 16) {
            aq2[0] = *(const float4*)(aP + (kc + 2) * 32);
            aq2[1] = *(const float4*)(aP + (kc + 2) * 32 + 4);
        }
        short8 af = pk8(aq0[0], aq0[1]);
#pragma unroll
        for (int c = 0; c < 8; ++c) {
            acc[c] = __builtin_amdgcn_mfma_f32_16x16x32_bf16(af, *(short8*)&bf[c], acc[c], 0, 0, 0);
            if (kc + 1 < 16) bf[c] = bW[(kc + 1) * 512 + c * 64];
        }
        aq0[0] = aq1[0]; aq0[1] = aq1[1];
        aq1[0] = aq2[0]; aq1[1] = aq2[1];
    }

    // epilogue: score = sum_col tanh(acc)*Wv[col] + bv
    float psum[4] = {};
#pragma unroll
    for (int c = 0; c < 8; ++c) {
        int col = c * 16 + m15;
        float wvv = WvS[col];
#pragma unroll
        for (int v = 0; v < 4; ++v)
            psum[v] += fast_tanh(acc[c][v]) * wvv;
    }
#pragma unroll
    for (int off = 1; off < 16; off <<= 1) {
#pragma unroll
        for (int v = 0; v < 4; ++v) psum[v] += __shfl_xor(psum[v], off);
    }
    if (m15 == 0) {
        float bvv = bv[0];
#pragma unroll
        for (int v = 0; v < 4; ++v)
            scores[r0 + wv * 16 + quad * 4 + v] = psum[v] + bvv;
    }
}

// ---------------------------------------------------------------------------
// Fused softmax + context phase 1. Each (b,p) block re-derives the row
// max/sum from scores (4 KB, L2-hot, deterministic & identical across p),
// writes attention weights for its chunk, and accumulates the weighted
// partial context. Removes the separate softmax launch.
// ---------------------------------------------------------------------------
__global__ __launch_bounds__(256) void ctx1_kernel(
    const float* __restrict__ values, const float* __restrict__ scores,
    float* __restrict__ attw, float* __restrict__ part)
{
    __shared__ float wS[CT_];
    __shared__ float4 ps[128];
    __shared__ float red[4];
    int b = blockIdx.x, p = blockIdx.y, tid = threadIdx.x;
    const float* sb = scores + b * T_;

    // full-row softmax normalization (max + sum)
    float v[4];
    int tv[4];
#pragma unroll
    for (int i = 0; i < 4; ++i) {
        int t = tid + i * 256;
        tv[i] = t;
        v[i] = (t < T_) ? sb[t] : -1e30f;
    }
    float mx = fmaxf(fmaxf(v[0], v[1]), fmaxf(v[2], v[3]));
#pragma unroll
    for (int off = 32; off >= 1; off >>= 1) mx = fmaxf(mx, __shfl_xor(mx, off));
    int wvi = tid >> 6, lane = tid & 63;
    if (lane == 0) red[wvi] = mx;
    __syncthreads();
    mx = fmaxf(fmaxf(red[0], red[1]), fmaxf(red[2], red[3]));
    float sum = 0.f;
#pragma unroll
    for (int i = 0; i < 4; ++i)
        sum += (tv[i] < T_) ? __expf(v[i] - mx) : 0.f;
#pragma unroll
    for (int off = 32; off >= 1; off >>= 1) sum += __shfl_xor(sum, off);
    __syncthreads();
    if (lane == 0) red[wvi] = sum;
    __syncthreads();
    float inv = 1.0f / (red[0] + red[1] + red[2] + red[3]);

    // this block's chunk: weights -> LDS + attw output
    int t0 = p * CT_;
    int len = (T_ - t0 < CT_) ? (T_ - t0) : CT_;
    if (tid < len) {
        float e = __expf(sb[t0 + tid] - mx) * inv;
        wS[tid] = e;
        attw[b * T_ + t0 + tid] = e;
    }
    __syncthreads();

    int cl = tid & 127, tp = tid >> 7;
    const float* vp = values + ((size_t)b * T_ + t0) * DV_ + cl * 4;
    float4 a = {0.f, 0.f, 0.f, 0.f};
#pragma unroll 4
    for (int t = tp; t < len; t += 2) {
        float4 vv = *(const float4*)(vp + (size_t)t * DV_);
        float wt = wS[t];
        a.x += wt * vv.x; a.y += wt * vv.y; a.z += wt * vv.z; a.w += wt * vv.w;
    }
    if (tp == 1) ps[cl] = a;
    __syncthreads();
    if (tp == 0) {
        float4 o = ps[cl];
        o.x += a.x; o.y += a.y; o.z += a.z; o.w += a.w;
        *(float4*)(part + ((size_t)(b * P_ + p)) * DV_ + cl * 4) = o;
    }
}

// context phase 2: ctx[b,d] = sum_p partial[b,p,d]
__global__ void ctx2_kernel(const float* __restrict__ part, float* __restrict__ ctx) {
    int b = blockIdx.x, tid = threadIdx.x;   // 128 threads, float4 each
    const float* pp = part + (size_t)b * P_ * DV_ + tid * 4;
    float4 s = {0.f, 0.f, 0.f, 0.f};
#pragma unroll
    for (int p = 0; p < P_; ++p) {
        float4 v = *(const float4*)(pp + (size_t)p * DV_);
        s.x += v.x; s.y += v.y; s.z += v.z; s.w += v.w;
    }
    *(float4*)(ctx + (size_t)b * DV_ + tid * 4) = s;
}

extern "C" void kernel_launch(void* const* d_in, const int* in_sizes, int n_in,
                              void* d_out, int out_size, void* d_ws, size_t ws_size,
                              hipStream_t stream) {
    const float* query  = (const float*)d_in[0];
    const float* values = (const float*)d_in[1];
    const float* prev   = (const float*)d_in[2];
    const float* Wq     = (const float*)d_in[3];
    const float* bq     = (const float*)d_in[4];
    const float* Wm     = (const float*)d_in[5];
    const float* bm     = (const float*)d_in[6];
    const float* Wv     = (const float*)d_in[7];
    const float* bv     = (const float*)d_in[8];
    const float* Wc     = (const float*)d_in[9];
    const float* Wl     = (const float*)d_in[10];

    float* out  = (float*)d_out;
    float* ctx  = out;                 // [64,512]
    float* attw = out + B_ * DV_;      // [64,1000,1]

    char* ws = (char*)d_ws;
    // ctx partials [0, 2M) -- ALIASED with qb partials [0, 512K):
    // partQ is dead once score_kernel completes; ctx1 writes part afterwards.
    float* part   = (float*)(ws);                              // 2 MB
    float* partQ  = (float*)(ws);                              // 512 KB (alias)
    float* scores = (float*)(ws + 2097152);                    // 256 KB
    short* WmX    = (short*)(ws + 2097152 + 262144);           // 128 KB
    short* WlX    = (short*)(ws + 2097152 + 262144 + 131072);  // 8 KB

    prep_kernel<<<73, 1024, 0, stream>>>(Wm, Wl, query, Wq, WmX, WlX, partQ);
    score_kernel<<<1000, 256, 0, stream>>>(values, prev, Wc, Wv, bv, WmX, WlX,
                                           partQ, bq, bm, scores);
    ctx1_kernel<<<dim3(B_, P_), 256, 0, stream>>>(values, scores, attw, part);
    ctx2_kernel<<<B_, 128, 0, stream>>>(part, ctx);
}

// Round 4
// 265.561 us; speedup vs baseline: 1.3116x; 1.2637x over previous
//
#include <hip/hip_runtime.h>

#define B_  64
#define T_  1000
#define DV_ 512
#define DQ_ 1024
#define U_  128
#define F_  32
#define KS_ 31
#define P_  16     // context partial chunks per batch
#define CT_ 63     // t per chunk (last chunk 55)

typedef __attribute__((ext_vector_type(8))) short short8;
typedef __attribute__((ext_vector_type(4))) float f32x4;

// round-to-nearest-even f32 -> bf16 (bit trick), packed pair
__device__ __forceinline__ unsigned pk2(float a, float b) {
    union { float f; unsigned u; } x, y;
    x.f = a; y.f = b;
    unsigned ra = (x.u + 0x7FFFu + ((x.u >> 16) & 1u)) >> 16;
    unsigned rb = (y.u + 0x7FFFu + ((y.u >> 16) & 1u)) >> 16;
    return (ra & 0xFFFFu) | (rb << 16);
}

__device__ __forceinline__ float fast_tanh(float x) {
    return 1.0f - 2.0f / (__expf(2.0f * x) + 1.0f);
}

// pack two float4 (8 consecutive k) into bf16 short8
__device__ __forceinline__ short8 pk8(float4 f0, float4 f1) {
    int4 q;
    q.x = pk2(f0.x, f0.y); q.y = pk2(f0.z, f0.w);
    q.z = pk2(f1.x, f1.y); q.w = pk2(f1.z, f1.w);
    return *(short8*)&q;
}

// ---------------------------------------------------------------------------
// Merged prep: blocks 0..8 repack Wm/Wl to bf16 B-frag layout.
// Blocks 9..72: qb k-split partials. Block id -> (slab s of 64 k, batch-group
// bg of 16 b). Wq traffic = 4x512KB total; 64 blocks stream in parallel.
// partQ[s][b][u] reduced inside score_kernel (with bq+bm).
// ---------------------------------------------------------------------------
__global__ __launch_bounds__(1024) void prep_kernel(
    const float* __restrict__ Wm, const float* __restrict__ Wl,
    const float* __restrict__ query, const float* __restrict__ Wq,
    short* __restrict__ WmX, short* __restrict__ WlX, float* __restrict__ partQ)
{
    __shared__ float sh[1024];
    int blk = blockIdx.x, tid = threadIdx.x;
    if (blk < 9) {
        int g = blk * 1024 + tid;
        if (g < 8192) {
            int kc = g >> 9, e = g & 511;
            int n = e >> 2, q = e & 3;
            int kb = kc * 32 + q * 8;
            int4 p;
            p.x = pk2(Wm[(kb + 0) * U_ + n], Wm[(kb + 1) * U_ + n]);
            p.y = pk2(Wm[(kb + 2) * U_ + n], Wm[(kb + 3) * U_ + n]);
            p.z = pk2(Wm[(kb + 4) * U_ + n], Wm[(kb + 5) * U_ + n]);
            p.w = pk2(Wm[(kb + 6) * U_ + n], Wm[(kb + 7) * U_ + n]);
            ((int4*)WmX)[g] = p;
        } else if (g < 8704) {
            int e = g - 8192;
            int n = e >> 2, q = e & 3;
            int kb = q * 8;
            int4 p;
            p.x = pk2(Wl[(kb + 0) * U_ + n], Wl[(kb + 1) * U_ + n]);
            p.y = pk2(Wl[(kb + 2) * U_ + n], Wl[(kb + 3) * U_ + n]);
            p.z = pk2(Wl[(kb + 4) * U_ + n], Wl[(kb + 5) * U_ + n]);
            p.w = pk2(Wl[(kb + 6) * U_ + n], Wl[(kb + 7) * U_ + n]);
            ((int4*)WlX)[e] = p;
        }
    } else {
        int id = blk - 9;          // 0..63
        int s  = id >> 2;          // k-slab 0..15  (64 k each)
        int bg = id & 3;           // batch group 0..3 (16 b each)
        // stage query tile [16 b][64 k]
        sh[tid] = query[(size_t)(bg * 16 + (tid >> 6)) * DQ_ + s * 64 + (tid & 63)];
        __syncthreads();
        int u = tid & 127, h = tid >> 7;   // h 0..7, each handles 2 batches
        const float* wp = Wq + (size_t)(s * 64) * U_ + u;
        const float* q0 = sh + (h * 2) * 64;
        const float* q1 = q0 + 64;
        float a0 = 0.f, a1 = 0.f;
#pragma unroll 8
        for (int k = 0; k < 64; ++k) {
            float w = wp[(size_t)k * U_];
            a0 += q0[k] * w; a1 += q1[k] * w;
        }
        int b0i = bg * 16 + h * 2;
        partQ[s * 8192 + b0i * 128 + u]       = a0;
        partQ[s * 8192 + (b0i + 1) * 128 + u] = a1;
    }
}

// ---------------------------------------------------------------------------
// scores[r], r=b*T+t: tanh(values@Wm + qb + tanh(conv(prev)@Wl)) @ Wv + bv
// 64 rows/block (1000 blocks), 4 waves; each wave owns ONE 16-row group x
// 128 cols. PLAIN launch_bounds(256): any min-waves hint makes the gfx950
// unified-file allocator partition arch/acc below natural demand and spill
// 200+ MB to scratch ((256,4): VGPR=64, 251 MB; (256,3): VGPR=84, 207 MB).
// Natural demand ~150 regs -> 3 waves/SIMD without spill.
// Barrier-free streaming K-loop: A dist-2, B in-place dist-1.
// ---------------------------------------------------------------------------
__global__ __launch_bounds__(256) void score_kernel(
    const float* __restrict__ values, const float* __restrict__ prev,
    const float* __restrict__ Wc, const float* __restrict__ Wv,
    const float* __restrict__ bv, const short* __restrict__ WmX,
    const short* __restrict__ WlX, const float* __restrict__ partQ,
    const float* __restrict__ bq, const float* __restrict__ bm,
    float* __restrict__ scores)
{
    __shared__ float WcS[KS_ * F_];
    __shared__ short AsL[64 * 32];     // conv result, A-frag layout + XOR swizzle
    __shared__ float qbS[2 * U_];
    __shared__ float WvS[U_];

    const int tid = threadIdx.x;
    const int r0 = blockIdx.x * 64;
    const int b0 = r0 / T_;
    const int b1 = (r0 + 63) / T_;

    for (int i = tid; i < KS_ * F_; i += 256) WcS[i] = Wc[i];
    if (tid < U_) WvS[tid] = Wv[tid];
    {
        int u = tid & (U_ - 1);
        int bb = (tid < U_) ? b0 : b1;
        float s = bq[u] + bm[u];
#pragma unroll
        for (int sl = 0; sl < 16; ++sl) s += partQ[sl * 8192 + bb * 128 + u];
        qbS[tid] = s;
    }

    const int wv = tid >> 6, lane = tid & 63;
    const int quad = lane >> 4, m15 = lane & 15;
    const int row0 = wv * 16 + m15;          // this wave's A row in tile
    const float* aP = values + (size_t)(r0 + row0) * DV_ + quad * 8;
    const int4* bW  = (const int4*)WmX + m15 * 4 + quad;
    const int4* blW = (const int4*)WlX + m15 * 4 + quad;

    // prefetch: A for kc=0,1 ; B for kc=0 (stay in flight across conv/barriers)
    float4 aq0[2], aq1[2], aq2[2];
    int4 bf[8];
    aq0[0] = *(const float4*)(aP);      aq0[1] = *(const float4*)(aP + 4);
    aq1[0] = *(const float4*)(aP + 32); aq1[1] = *(const float4*)(aP + 36);
#pragma unroll
    for (int c = 0; c < 8; ++c) bf[c] = bW[c * 64];

    __syncthreads();   // WcS / qbS / WvS ready

    // location conv: loc_pre[i,f] = sum_k prev[b, t+k-15]*Wc[k,f] (SAME pad)
    // 256 (row, 8-filter-group) items, 1 per thread.
    {
        int i = tid & 63, fg = tid >> 6;
        int r = r0 + i;
        int b = r / T_;
        int t = r - b * T_;
        const float* pv = prev + b * T_;
        float a8[8] = {};
#pragma unroll
        for (int k = 0; k < KS_; ++k) {
            int tt = t + k - 15;
            float p = ((unsigned)tt < (unsigned)T_) ? pv[tt] : 0.f;
#pragma unroll
            for (int j = 0; j < 8; ++j) a8[j] += p * WcS[k * F_ + fg * 8 + j];
        }
        int4 pq;
        pq.x = pk2(a8[0], a8[1]); pq.y = pk2(a8[2], a8[3]);
        pq.z = pk2(a8[4], a8[5]); pq.w = pk2(a8[6], a8[7]);
        ((int4*)AsL)[i * 4 + (fg ^ ((i >> 1) & 3))] = pq;   // XOR swizzle
    }
    __syncthreads();

    // loc GEMM (K=32) into acc, then acc = qb + tanh(acc)
    f32x4 acc[8] = {};
    {
        short8 afl = ((const short8*)AsL)[row0 * 4 + (quad ^ ((row0 >> 1) & 3))];
#pragma unroll
        for (int c = 0; c < 8; ++c) {
            int4 bl = blW[c * 64];
            acc[c] = __builtin_amdgcn_mfma_f32_16x16x32_bf16(afl, *(short8*)&bl, acc[c], 0, 0, 0);
        }
        int qoff[4];
#pragma unroll
        for (int v = 0; v < 4; ++v) {
            int r = r0 + wv * 16 + quad * 4 + v;
            qoff[v] = ((r / T_) == b0) ? 0 : U_;
        }
#pragma unroll
        for (int c = 0; c < 8; ++c) {
            int col = c * 16 + m15;
#pragma unroll
            for (int v = 0; v < 4; ++v)
                acc[c][v] = qbS[qoff[v] + col] + fast_tanh(acc[c][v]);
        }
    }

    // barrier-free streaming main loop: A dist-2 queue, B dist-1 via
    // in-place reload (bf[c] reused right after its MFMA consumes it).
#pragma unroll
    for (int kc = 0; kc < 16; ++kc) {
        if (kc + 2 < 16) {
            aq2[0] = *(const float4*)(aP + (kc + 2) * 32);
            aq2[1] = *(const float4*)(aP + (kc + 2) * 32 + 4);
        }
        short8 af = pk8(aq0[0], aq0[1]);
#pragma unroll
        for (int c = 0; c < 8; ++c) {
            acc[c] = __builtin_amdgcn_mfma_f32_16x16x32_bf16(af, *(short8*)&bf[c], acc[c], 0, 0, 0);
            if (kc + 1 < 16) bf[c] = bW[(kc + 1) * 512 + c * 64];
        }
        aq0[0] = aq1[0]; aq0[1] = aq1[1];
        aq1[0] = aq2[0]; aq1[1] = aq2[1];
    }

    // epilogue: score = sum_col tanh(acc)*Wv[col] + bv
    float psum[4] = {};
#pragma unroll
    for (int c = 0; c < 8; ++c) {
        int col = c * 16 + m15;
        float wvv = WvS[col];
#pragma unroll
        for (int v = 0; v < 4; ++v)
            psum[v] += fast_tanh(acc[c][v]) * wvv;
    }
#pragma unroll
    for (int off = 1; off < 16; off <<= 1) {
#pragma unroll
        for (int v = 0; v < 4; ++v) psum[v] += __shfl_xor(psum[v], off);
    }
    if (m15 == 0) {
        float bvv = bv[0];
#pragma unroll
        for (int v = 0; v < 4; ++v)
            scores[r0 + wv * 16 + quad * 4 + v] = psum[v] + bvv;
    }
}

// ---------------------------------------------------------------------------
// Fused softmax + context phase 1. Each (b,p) block re-derives the row
// max/sum from scores (4 KB, L2-hot, deterministic & identical across p),
// writes attention weights for its chunk, and accumulates the weighted
// partial context. Removes the separate softmax launch.
// ---------------------------------------------------------------------------
__global__ __launch_bounds__(256) void ctx1_kernel(
    const float* __restrict__ values, const float* __restrict__ scores,
    float* __restrict__ attw, float* __restrict__ part)
{
    __shared__ float wS[CT_];
    __shared__ float4 ps[128];
    __shared__ float red[4];
    int b = blockIdx.x, p = blockIdx.y, tid = threadIdx.x;
    const float* sb = scores + b * T_;

    // full-row softmax normalization (max + sum)
    float v[4];
    int tv[4];
#pragma unroll
    for (int i = 0; i < 4; ++i) {
        int t = tid + i * 256;
        tv[i] = t;
        v[i] = (t < T_) ? sb[t] : -1e30f;
    }
    float mx = fmaxf(fmaxf(v[0], v[1]), fmaxf(v[2], v[3]));
#pragma unroll
    for (int off = 32; off >= 1; off >>= 1) mx = fmaxf(mx, __shfl_xor(mx, off));
    int wvi = tid >> 6, lane = tid & 63;
    if (lane == 0) red[wvi] = mx;
    __syncthreads();
    mx = fmaxf(fmaxf(red[0], red[1]), fmaxf(red[2], red[3]));
    float sum = 0.f;
#pragma unroll
    for (int i = 0; i < 4; ++i)
        sum += (tv[i] < T_) ? __expf(v[i] - mx) : 0.f;
#pragma unroll
    for (int off = 32; off >= 1; off >>= 1) sum += __shfl_xor(sum, off);
    __syncthreads();
    if (lane == 0) red[wvi] = sum;
    __syncthreads();
    float inv = 1.0f / (red[0] + red[1] + red[2] + red[3]);

    // this block's chunk: weights -> LDS + attw output
    int t0 = p * CT_;
    int len = (T_ - t0 < CT_) ? (T_ - t0) : CT_;
    if (tid < len) {
        float e = __expf(sb[t0 + tid] - mx) * inv;
        wS[tid] = e;
        attw[b * T_ + t0 + tid] = e;
    }
    __syncthreads();

    int cl = tid & 127, tp = tid >> 7;
    const float* vp = values + ((size_t)b * T_ + t0) * DV_ + cl * 4;
    float4 a = {0.f, 0.f, 0.f, 0.f};
#pragma unroll 4
    for (int t = tp; t < len; t += 2) {
        float4 vv = *(const float4*)(vp + (size_t)t * DV_);
        float wt = wS[t];
        a.x += wt * vv.x; a.y += wt * vv.y; a.z += wt * vv.z; a.w += wt * vv.w;
    }
    if (tp == 1) ps[cl] = a;
    __syncthreads();
    if (tp == 0) {
        float4 o = ps[cl];
        o.x += a.x; o.y += a.y; o.z += a.z; o.w += a.w;
        *(float4*)(part + ((size_t)(b * P_ + p)) * DV_ + cl * 4) = o;
    }
}

// context phase 2: ctx[b,d] = sum_p partial[b,p,d]
__global__ void ctx2_kernel(const float* __restrict__ part, float* __restrict__ ctx) {
    int b = blockIdx.x, tid = threadIdx.x;   // 128 threads, float4 each
    const float* pp = part + (size_t)b * P_ * DV_ + tid * 4;
    float4 s = {0.f, 0.f, 0.f, 0.f};
#pragma unroll
    for (int p = 0; p < P_; ++p) {
        float4 v = *(const float4*)(pp + (size_t)p * DV_);
        s.x += v.x; s.y += v.y; s.z += v.z; s.w += v.w;
    }
    *(float4*)(ctx + (size_t)b * DV_ + tid * 4) = s;
}

extern "C" void kernel_launch(void* const* d_in, const int* in_sizes, int n_in,
                              void* d_out, int out_size, void* d_ws, size_t ws_size,
                              hipStream_t stream) {
    const float* query  = (const float*)d_in[0];
    const float* values = (const float*)d_in[1];
    const float* prev   = (const float*)d_in[2];
    const float* Wq     = (const float*)d_in[3];
    const float* bq     = (const float*)d_in[4];
    const float* Wm     = (const float*)d_in[5];
    const float* bm     = (const float*)d_in[6];
    const float* Wv     = (const float*)d_in[7];
    const float* bv     = (const float*)d_in[8];
    const float* Wc     = (const float*)d_in[9];
    const float* Wl     = (const float*)d_in[10];

    float* out  = (float*)d_out;
    float* ctx  = out;                 // [64,512]
    float* attw = out + B_ * DV_;      // [64,1000,1]

    char* ws = (char*)d_ws;
    // ctx partials [0, 2M) -- ALIASED with qb partials [0, 512K):
    // partQ is dead once score_kernel completes; ctx1 writes part afterwards.
    float* part   = (float*)(ws);                              // 2 MB
    float* partQ  = (float*)(ws);                              // 512 KB (alias)
    float* scores = (float*)(ws + 2097152);                    // 256 KB
    short* WmX    = (short*)(ws + 2097152 + 262144);           // 128 KB
    short* WlX    = (short*)(ws + 2097152 + 262144 + 131072);  // 8 KB

    prep_kernel<<<73, 1024, 0, stream>>>(Wm, Wl, query, Wq, WmX, WlX, partQ);
    score_kernel<<<1000, 256, 0, stream>>>(values, prev, Wc, Wv, bv, WmX, WlX,
                                           partQ, bq, bm, scores);
    ctx1_kernel<<<dim3(B_, P_), 256, 0, stream>>>(values, scores, attw, part);
    ctx2_kernel<<<B_, 128, 0, stream>>>(part, ctx);
}